// Round 2
// baseline (203.221 us; speedup 1.0000x reference)
//
#include <hip/hip_runtime.h>

// TopKRouter: logits = hs[32768,4096] @ gate_w[64,4096]^T ; top-2 + softmax.
// f32 GEMM emulated via 3-way bf16 split (6 MFMA products, si+sj<=2):
// residual ~2^-27 per term -> logit error ~1e-7 (index-exact vs f32 ref).
// NOTE: d_out is ONE float32 buffer; indices are written as float values.
// LDS kept at 48 KiB (static __shared__ must stay < 64 KiB or launch fails).

#define NT   256
#define TT   32768
#define HD   4096
#define NE   64
#define BMT  64
#define BKT  64
#define NKT  (HD / BKT)   // 64 K-steps

typedef __attribute__((ext_vector_type(8))) short bf16x8;
typedef __attribute__((ext_vector_type(4))) float f32x4;

#define MFMA __builtin_amdgcn_mfma_f32_16x16x32_bf16

__device__ __forceinline__ unsigned rne_bf16(float f) {
  unsigned u = __float_as_uint(f);
  return (u + 0x7fffu + ((u >> 16) & 1u)) >> 16;  // RNE to bf16, bits in low 16
}

// Split 8 f32 into three bf16x8 (hi/mid/lo), packed as uint4 (16B each).
__device__ __forceinline__ void split8(float4 a, float4 b,
                                       uint4& o0, uint4& o1, uint4& o2) {
  float f[8] = {a.x, a.y, a.z, a.w, b.x, b.y, b.z, b.w};
  unsigned h0[8], h1[8], h2[8];
#pragma unroll
  for (int j = 0; j < 8; ++j) {
    float x = f[j];
    unsigned u0 = rne_bf16(x);
    float g0 = __uint_as_float(u0 << 16);
    float r1 = x - g0;            // exact (Sterbenz)
    unsigned u1 = rne_bf16(r1);
    float g1 = __uint_as_float(u1 << 16);
    float r2 = r1 - g1;           // exact
    h0[j] = u0; h1[j] = u1; h2[j] = rne_bf16(r2);
  }
  o0 = make_uint4(h0[0]|(h0[1]<<16), h0[2]|(h0[3]<<16), h0[4]|(h0[5]<<16), h0[6]|(h0[7]<<16));
  o1 = make_uint4(h1[0]|(h1[1]<<16), h1[2]|(h1[3]<<16), h1[4]|(h1[5]<<16), h1[6]|(h1[7]<<16));
  o2 = make_uint4(h2[0]|(h2[1]<<16), h2[2]|(h2[3]<<16), h2[4]|(h2[5]<<16), h2[6]|(h2[7]<<16));
}

// LDS layout (single buffer, 48 KiB):
//   A splits s=0..2: byte base s*8192,          tile [64 rows][64 bf16] = 128 B/row
//   B splits s=0..2: byte base 24576 + s*8192,  tile [64 rows][64 bf16]
// XOR swizzle within each 128-B row: byte ^= (row&7)<<4  (kills 16-way conflicts)

__global__ __launch_bounds__(NT, 2)
void topk_router_kernel(const float* __restrict__ A, const float* __restrict__ W,
                        float* __restrict__ outw, float* __restrict__ outi,
                        float* __restrict__ outl) {
  __shared__ __align__(16) unsigned char smem[49152];

  const int tid  = threadIdx.x;
  const int bm   = blockIdx.x;
  const int lane = tid & 63;
  const int wid  = tid >> 6;     // 0..3
  const int wr   = wid >> 1;     // 0..1 (M wave coord)
  const int wc   = wid & 1;      // 0..1 (N wave coord)
  const int l15  = lane & 15;
  const int lg   = lane >> 4;    // 0..3

  // Staging: each thread owns one 64-B chunk of one A row and one B row.
  const int a_r = tid >> 2;            // 0..63
  const int a_c = (tid & 3) << 4;      // {0,16,32,48} f32 elems

  const float* aptr = A + ((size_t)(bm * BMT + a_r)) * HD + a_c;
  const float* bptr = W + ((size_t)a_r) * HD + a_c;

  const unsigned sw  = ((unsigned)(a_r & 7)) << 4;
  const unsigned cw0 = (unsigned)(a_r * 128) + (((unsigned)(a_c * 2 +  0)) ^ sw);
  const unsigned cw1 = (unsigned)(a_r * 128) + (((unsigned)(a_c * 2 + 16)) ^ sw);

  float4 av0, av1, av2, av3, bv0, bv1, bv2, bv3;

  f32x4 acc00 = {0.f, 0.f, 0.f, 0.f};
  f32x4 acc01 = {0.f, 0.f, 0.f, 0.f};
  f32x4 acc10 = {0.f, 0.f, 0.f, 0.f};
  f32x4 acc11 = {0.f, 0.f, 0.f, 0.f};

  auto stage = [&](int k0) {
    const float4* ap = (const float4*)(aptr + k0);
    av0 = ap[0]; av1 = ap[1]; av2 = ap[2]; av3 = ap[3];
    const float4* bp = (const float4*)(bptr + k0);
    bv0 = bp[0]; bv1 = bp[1]; bv2 = bp[2]; bv3 = bp[3];
  };

  auto convwrite = [&]() {
    uint4 o0, o1, o2;
    split8(av0, av1, o0, o1, o2);
    *(uint4*)(smem +     0 + cw0) = o0;
    *(uint4*)(smem +  8192 + cw0) = o1;
    *(uint4*)(smem + 16384 + cw0) = o2;
    split8(av2, av3, o0, o1, o2);
    *(uint4*)(smem +     0 + cw1) = o0;
    *(uint4*)(smem +  8192 + cw1) = o1;
    *(uint4*)(smem + 16384 + cw1) = o2;
    split8(bv0, bv1, o0, o1, o2);
    *(uint4*)(smem + 24576 + cw0) = o0;
    *(uint4*)(smem + 32768 + cw0) = o1;
    *(uint4*)(smem + 40960 + cw0) = o2;
    split8(bv2, bv3, o0, o1, o2);
    *(uint4*)(smem + 24576 + cw1) = o0;
    *(uint4*)(smem + 32768 + cw1) = o1;
    *(uint4*)(smem + 40960 + cw1) = o2;
  };

  auto compute = [&]() {
#pragma unroll
    for (int ks = 0; ks < 2; ++ks) {
      bf16x8 a0m0, a0m1, a1m0, a1m1, a2m0, a2m1;
      bf16x8 b0n0, b0n1, b1n0, b1n1, b2n0, b2n1;
      const unsigned kb = (unsigned)(ks * 64 + lg * 16);
#define LDA(SI, MI, DST) { \
      int row = wr * 32 + (MI) * 16 + l15; \
      DST = *(const bf16x8*)(smem + (SI) * 8192 + row * 128 + (kb ^ (((unsigned)(row & 7)) << 4))); }
#define LDB(SI, NI, DST) { \
      int row = wc * 32 + (NI) * 16 + l15; \
      DST = *(const bf16x8*)(smem + 24576 + (SI) * 8192 + row * 128 + (kb ^ (((unsigned)(row & 7)) << 4))); }
      LDA(0, 0, a0m0) LDA(0, 1, a0m1)
      LDA(1, 0, a1m0) LDA(1, 1, a1m1)
      LDA(2, 0, a2m0) LDA(2, 1, a2m1)
      LDB(0, 0, b0n0) LDB(0, 1, b0n1)
      LDB(1, 0, b1n0) LDB(1, 1, b1n1)
      LDB(2, 0, b2n0) LDB(2, 1, b2n1)
#undef LDA
#undef LDB
#define PROD(AI, BI) \
      acc00 = MFMA(a##AI##m0, b##BI##n0, acc00, 0, 0, 0); \
      acc01 = MFMA(a##AI##m0, b##BI##n1, acc01, 0, 0, 0); \
      acc10 = MFMA(a##AI##m1, b##BI##n0, acc10, 0, 0, 0); \
      acc11 = MFMA(a##AI##m1, b##BI##n1, acc11, 0, 0, 0);
      // smallest-magnitude products first
      PROD(0, 2) PROD(1, 1) PROD(2, 0) PROD(0, 1) PROD(1, 0) PROD(0, 0)
#undef PROD
    }
  };

  // Prologue
  stage(0);
  convwrite();
  __syncthreads();

  for (int kt = 0; kt < NKT; ++kt) {
    const bool more = (kt + 1 < NKT);
    if (more) stage((kt + 1) * BKT);   // loads in flight across compute
    compute();
    __syncthreads();                   // all waves done reading LDS
    if (more) convwrite();             // vmcnt wait lands here, post-compute
    __syncthreads();
  }

  // ---- Epilogue: write logits (global + LDS), then top-2 + softmax ----
  const int t0 = bm * BMT;
  float* lf = (float*)smem;            // [64][65] f32, pad kills bank conflicts

#define EPI(MI, NI, ACC) \
  { _Pragma("unroll") \
    for (int r = 0; r < 4; ++r) { \
      int tl = wr * 32 + (MI) * 16 + lg * 4 + r; \
      int e  = wc * 32 + (NI) * 16 + l15; \
      float v = ACC[r]; \
      outl[(size_t)(t0 + tl) * NE + e] = v; \
      lf[tl * 65 + e] = v; \
    } }
  EPI(0, 0, acc00) EPI(0, 1, acc01) EPI(1, 0, acc10) EPI(1, 1, acc11)
#undef EPI

  __syncthreads();

  if (tid < BMT) {
    const int t = tid;
    float m1 = -1e30f, m2 = -1e30f;
    int i1 = 0, i2 = 0;
#pragma unroll
    for (int e = 0; e < NE; ++e) {
      float v = lf[t * 65 + e];
      if (v > m1)      { m2 = m1; i2 = i1; m1 = v; i1 = e; }
      else if (v > m2) { m2 = v; i2 = e; }
    }
    float e2  = expf(m2 - m1);
    float inv = 1.0f / (1.0f + e2);
    outw[(size_t)(t0 + t) * 2 + 0] = inv;
    outw[(size_t)(t0 + t) * 2 + 1] = e2 * inv;
    // d_out is a single float32 buffer: indices must be numeric floats.
    outi[(size_t)(t0 + t) * 2 + 0] = (float)i1;
    outi[(size_t)(t0 + t) * 2 + 1] = (float)i2;
  }
}

extern "C" void kernel_launch(void* const* d_in, const int* in_sizes, int n_in,
                              void* d_out, int out_size, void* d_ws, size_t ws_size,
                              hipStream_t stream) {
  (void)in_sizes; (void)n_in; (void)d_ws; (void)ws_size; (void)out_size;
  const float* A = (const float*)d_in[0];   // hidden_states [32768][4096] f32
  const float* W = (const float*)d_in[1];   // gate_w [64][4096] f32
  float* outw = (float*)d_out;              // [T][2] f32 weights
  float* outi = (float*)d_out + 2 * TT;     // [T][2] indices AS FLOATS
  float* outl = (float*)d_out + 4 * TT;     // [T][64] f32 logits

  dim3 grid(TT / BMT);   // 512 blocks
  dim3 block(NT);        // 256 threads
  hipLaunchKernelGGL(topk_router_kernel, grid, block, 0, stream, A, W, outw, outi, outl);
}

// Round 3
// 168.529 us; speedup vs baseline: 1.2059x; 1.2059x over previous
//
#include <hip/hip_runtime.h>

// TopKRouter: logits = hs[32768,4096] @ gate_w[64,4096]^T ; top-2 + softmax.
// f32 GEMM via 3-limb TRUNCATION split (exact residuals; 6 MFMA products,
// si+sj<=2): logit error ~1e-8 -> index-exact vs f32 reference.
// Never-drain pipeline: BK=32 double-buffered LDS (48 KiB), 2 static reg
// sets, loads(k+2) issued before compute(k)/convert(k+1), 1 barrier/iter.
// Indices written as float values (single f32 out buffer).

#define NT   256
#define TT   32768
#define HD   4096
#define NE   64
#define BMT  64
#define BKT  32
#define NKT  (HD / BKT)   // 128 K-steps

typedef __attribute__((ext_vector_type(8))) short bf16x8;
typedef __attribute__((ext_vector_type(4))) float f32x4;

#define MFMA __builtin_amdgcn_mfma_f32_16x16x32_bf16

// Exact 3-limb truncation split of 8 f32 -> 3 packed bf16x8 (as uint4).
// limb0 = trunc_bf16(x); r1 = x - limb0 (exact); limb1 = trunc_bf16(r1);
// r2 = r1 - limb1 (exact); limb2 = trunc_bf16(r2). Dropped residual 2^-24|x|.
__device__ __forceinline__ void tsplit8(float4 a, float4 b,
                                        uint4& o0, uint4& o1, uint4& o2) {
  float f[8] = {a.x, a.y, a.z, a.w, b.x, b.y, b.z, b.w};
  unsigned p0[4], p1[4], p2[4];
#pragma unroll
  for (int j = 0; j < 4; ++j) {
    float x0 = f[2 * j], x1 = f[2 * j + 1];
    unsigned u0 = __float_as_uint(x0) & 0xffff0000u;
    unsigned u1 = __float_as_uint(x1) & 0xffff0000u;
    float r0 = x0 - __uint_as_float(u0);
    float r1 = x1 - __uint_as_float(u1);
    unsigned v0 = __float_as_uint(r0) & 0xffff0000u;
    unsigned v1 = __float_as_uint(r1) & 0xffff0000u;
    float s0 = r0 - __uint_as_float(v0);
    float s1 = r1 - __uint_as_float(v1);
    p0[j] = (u0 >> 16) | u1;
    p1[j] = (v0 >> 16) | v1;
    p2[j] = (__float_as_uint(s0) >> 16) | (__float_as_uint(s1) & 0xffff0000u);
  }
  o0 = make_uint4(p0[0], p0[1], p0[2], p0[3]);
  o1 = make_uint4(p1[0], p1[1], p1[2], p1[3]);
  o2 = make_uint4(p2[0], p2[1], p2[2], p2[3]);
}

// LDS: 2 buffers x 24 KiB. Per buffer: A limbs s=0..2 at s*4096,
// B limbs at 12288 + s*4096. Tile [64 rows][32 bf16] = 64 B/row.
// Swizzle (both write & read): byte ^= ((row>>1)&3)<<4.

__global__ __launch_bounds__(NT, 2)
void topk_router_kernel(const float* __restrict__ A, const float* __restrict__ W,
                        float* __restrict__ outw, float* __restrict__ outi,
                        float* __restrict__ outl) {
  __shared__ __align__(16) unsigned char smem[49152];

  const int tid  = threadIdx.x;
  const int bm   = blockIdx.x;
  const int lane = tid & 63;
  const int wid  = tid >> 6;     // 0..3
  const int wr   = wid >> 1;     // 0..1
  const int wc   = wid & 1;      // 0..1
  const int l15  = lane & 15;
  const int lg   = lane >> 4;    // 0..3

  // Staging: thread owns 8 f32 of one row (A and B same pattern).
  const int s_r  = tid >> 2;           // 0..63
  const int s_cb = (tid & 3) << 3;     // element offset {0,8,16,24}

  const float* aball = A + (size_t)(bm * BMT + s_r) * HD + s_cb;
  const float* bball = W + (size_t)s_r * HD + s_cb;

  const unsigned wswz  = ((unsigned)((s_r >> 1) & 3)) << 4;
  const unsigned wbyte = (unsigned)(s_r * 64) + (((unsigned)(s_cb * 2)) ^ wswz);

  f32x4 acc00 = {0.f,0.f,0.f,0.f}, acc01 = {0.f,0.f,0.f,0.f};
  f32x4 acc10 = {0.f,0.f,0.f,0.f}, acc11 = {0.f,0.f,0.f,0.f};

  float4 aE0, aE1, bE0, bE1;   // even tiles
  float4 aO0, aO1, bO0, bO1;   // odd tiles

#define LOADS(T, A0, A1, B0, B1) { \
    const float4* ap = (const float4*)(aball + (size_t)(T) * BKT); \
    A0 = ap[0]; A1 = ap[1]; \
    const float4* bp = (const float4*)(bball + (size_t)(T) * BKT); \
    B0 = bp[0]; B1 = bp[1]; }

#define CONVW(BB, A0, A1, B0, B1) { \
    uint4 o0, o1, o2; \
    tsplit8(A0, A1, o0, o1, o2); \
    *(uint4*)(smem + (BB) +     0 + wbyte) = o0; \
    *(uint4*)(smem + (BB) +  4096 + wbyte) = o1; \
    *(uint4*)(smem + (BB) +  8192 + wbyte) = o2; \
    tsplit8(B0, B1, o0, o1, o2); \
    *(uint4*)(smem + (BB) + 12288 + wbyte) = o0; \
    *(uint4*)(smem + (BB) + 16384 + wbyte) = o1; \
    *(uint4*)(smem + (BB) + 20480 + wbyte) = o2; }

  auto compute = [&](int bb) {
    bf16x8 a0m0, a0m1, a1m0, a1m1, a2m0, a2m1;
    bf16x8 b0n0, b0n1, b1n0, b1n1, b2n0, b2n1;
    const unsigned kb = (unsigned)(lg * 16);
#define LDA(SI, MI, DST) { \
    int row = wr * 32 + (MI) * 16 + l15; \
    DST = *(const bf16x8*)(smem + bb + (SI) * 4096 + row * 64 + \
          (kb ^ ((((unsigned)row >> 1) & 3) << 4))); }
#define LDB(SI, NI, DST) { \
    int row = wc * 32 + (NI) * 16 + l15; \
    DST = *(const bf16x8*)(smem + bb + 12288 + (SI) * 4096 + row * 64 + \
          (kb ^ ((((unsigned)row >> 1) & 3) << 4))); }
    LDA(0, 0, a0m0) LDA(0, 1, a0m1)
    LDA(1, 0, a1m0) LDA(1, 1, a1m1)
    LDA(2, 0, a2m0) LDA(2, 1, a2m1)
    LDB(0, 0, b0n0) LDB(0, 1, b0n1)
    LDB(1, 0, b1n0) LDB(1, 1, b1n1)
    LDB(2, 0, b2n0) LDB(2, 1, b2n1)
#undef LDA
#undef LDB
#define PROD(AI, BI) \
    acc00 = MFMA(a##AI##m0, b##BI##n0, acc00, 0, 0, 0); \
    acc01 = MFMA(a##AI##m0, b##BI##n1, acc01, 0, 0, 0); \
    acc10 = MFMA(a##AI##m1, b##BI##n0, acc10, 0, 0, 0); \
    acc11 = MFMA(a##AI##m1, b##BI##n1, acc11, 0, 0, 0);
    // smallest-magnitude products first
    PROD(0, 2) PROD(1, 1) PROD(2, 0) PROD(0, 1) PROD(1, 0) PROD(0, 0)
#undef PROD
  };

  // Prologue: tiles 0,1 in flight; convert tile 0 into buf0.
  LOADS(0, aE0, aE1, bE0, bE1)
  LOADS(1, aO0, aO1, bO0, bO1)
  CONVW(0, aE0, aE1, bE0, bE1)
  __syncthreads();

#pragma unroll 1
  for (int kk = 0; kk < NKT; kk += 2) {
    // ---- even iter: compute tile kk (buf0), convert tile kk+1 -> buf1 ----
    if (kk + 2 < NKT) { LOADS(kk + 2, aE0, aE1, bE0, bE1) }
    __builtin_amdgcn_sched_barrier(0);   // pin load issue before compute
    compute(0);
    CONVW(24576, aO0, aO1, bO0, bO1)
    __syncthreads();
    // ---- odd iter: compute tile kk+1 (buf1), convert tile kk+2 -> buf0 ----
    if (kk + 3 < NKT) { LOADS(kk + 3, aO0, aO1, bO0, bO1) }
    __builtin_amdgcn_sched_barrier(0);
    compute(24576);
    if (kk + 2 < NKT) { CONVW(0, aE0, aE1, bE0, bE1) }
    __syncthreads();
  }

  // ---- Epilogue: logits to global + LDS, then top-2 + softmax ----
  const int t0 = bm * BMT;
  float* lf = (float*)smem;            // [64][65] f32, pad kills conflicts

#define EPI(MI, NI, ACC) \
  { _Pragma("unroll") \
    for (int r = 0; r < 4; ++r) { \
      int tl = wr * 32 + (MI) * 16 + lg * 4 + r; \
      int e  = wc * 32 + (NI) * 16 + l15; \
      float v = ACC[r]; \
      outl[(size_t)(t0 + tl) * NE + e] = v; \
      lf[tl * 65 + e] = v; \
    } }
  EPI(0, 0, acc00) EPI(0, 1, acc01) EPI(1, 0, acc10) EPI(1, 1, acc11)
#undef EPI

  __syncthreads();

  if (tid < BMT) {
    const int t = tid;
    float m1 = -1e30f, m2 = -1e30f;
    int i1 = 0, i2 = 0;
#pragma unroll
    for (int e = 0; e < NE; ++e) {
      float v = lf[t * 65 + e];
      if (v > m1)      { m2 = m1; i2 = i1; m1 = v; i1 = e; }
      else if (v > m2) { m2 = v; i2 = e; }
    }
    float e2  = expf(m2 - m1);
    float inv = 1.0f / (1.0f + e2);
    outw[(size_t)(t0 + t) * 2 + 0] = inv;
    outw[(size_t)(t0 + t) * 2 + 1] = e2 * inv;
    outi[(size_t)(t0 + t) * 2 + 0] = (float)i1;   // indices as floats
    outi[(size_t)(t0 + t) * 2 + 1] = (float)i2;
  }
}

extern "C" void kernel_launch(void* const* d_in, const int* in_sizes, int n_in,
                              void* d_out, int out_size, void* d_ws, size_t ws_size,
                              hipStream_t stream) {
  (void)in_sizes; (void)n_in; (void)d_ws; (void)ws_size; (void)out_size;
  const float* A = (const float*)d_in[0];   // hidden_states [32768][4096] f32
  const float* W = (const float*)d_in[1];   // gate_w [64][4096] f32
  float* outw = (float*)d_out;              // [T][2] weights
  float* outi = (float*)d_out + 2 * TT;     // [T][2] indices AS FLOATS
  float* outl = (float*)d_out + 4 * TT;     // [T][64] logits

  dim3 grid(TT / BMT);   // 512 blocks
  dim3 block(NT);        // 256 threads
  hipLaunchKernelGGL(topk_router_kernel, grid, block, 0, stream, A, W, outw, outi, outl);
}